// Round 1
// baseline (356.690 us; speedup 1.0000x reference)
//
#include <hip/hip_runtime.h>

typedef unsigned int u32;
typedef unsigned short u16;
typedef short short8v __attribute__((ext_vector_type(8)));
typedef float f32x4 __attribute__((ext_vector_type(4)));

#define ND 1024
#define NH 16
#define OUT_T ((size_t)16777216)  // 2*16*8192*64 elements per stacked tensor

__device__ __forceinline__ u16 f2bf(float f) {
  u32 u = __float_as_uint(f);
  u32 r = u + 0x7fffu + ((u >> 16) & 1u);
  return (u16)(r >> 16);
}

__device__ __forceinline__ short8v pack8(float4 a, float4 b) {
  short8v v;
  v[0] = (short)f2bf(a.x); v[1] = (short)f2bf(a.y);
  v[2] = (short)f2bf(a.z); v[3] = (short)f2bf(a.w);
  v[4] = (short)f2bf(b.x); v[5] = (short)f2bf(b.y);
  v[6] = (short)f2bf(b.z); v[7] = (short)f2bf(b.w);
  return v;
}

__device__ __forceinline__ void st16(float* p, const float* v) {
  for (int i = 0; i < 4; ++i) {
    f32x4 t; t[0] = v[4*i]; t[1] = v[4*i+1]; t[2] = v[4*i+2]; t[3] = v[4*i+3];
    *(f32x4*)(p + 4*i) = t;
  }
}

// ---- kernel 0: weights -> WT[w][c][kswz] bf16, transposed + swizzled ----
// kswz chunk: stored position of original k-chunk kc is kc ^ (c&7) (16B chunks of 8 bf16)
__global__ void k_wt(const float* __restrict__ w0, const float* __restrict__ w1,
                     const float* __restrict__ w2, const float* __restrict__ w3,
                     u16* __restrict__ WT) {
  __shared__ float T[64][65];
  int bid = blockIdx.x;
  int w = bid >> 8;
  int tk = (bid >> 4) & 15, tc = bid & 15;
  const float* W = w == 0 ? w0 : w == 1 ? w1 : w == 2 ? w2 : w3;
  int k0 = tk << 6, c0 = tc << 6;
  int tid = threadIdx.x;
  for (int it = 0; it < 16; ++it) {
    int idx = it * 256 + tid;
    int kk = idx >> 6, cc = idx & 63;
    T[kk][cc] = W[(size_t)(k0 + kk) * ND + c0 + cc];
  }
  __syncthreads();
  for (int it = 0; it < 2; ++it) {
    int ci = it * 256 + tid;
    int cc = ci >> 3, k8 = ci & 7;
    int c = c0 + cc;
    short8v v;
    for (int j = 0; j < 8; ++j) v[j] = (short)f2bf(T[k8 * 8 + j][cc]);
    size_t off = ((size_t)(w * ND + c) << 10) + k0 + (((k8 ^ c) & 7) << 3);
    *(short8v*)(WT + off) = v;
  }
}

// ---- kernel 1: lr projection -> E[b*16+h][seq] = sigmoid(x.lrw_h + lrb_h)/4096 ----
__global__ void k_lr(const float* __restrict__ X, const float* __restrict__ LW,
                     const float* __restrict__ LB, float* __restrict__ E) {
  int tid = threadIdx.x;
  int lane = tid & 63;
  int s = blockIdx.x * 4 + (tid >> 6);
  float xr[16];
  const float* xp = X + (size_t)s * ND + lane;
  for (int i = 0; i < 16; ++i) xr[i] = xp[i * 64];
  float myv = 0.f;
  for (int h = 0; h < NH; ++h) {
    const float* wp = LW + h * ND + lane;
    float acc = 0.f;
    for (int i = 0; i < 16; ++i) acc += xr[i] * wp[i * 64];
    for (int off = 32; off; off >>= 1) acc += __shfl_xor(acc, off);
    if (lane == h) myv = acc;
  }
  if (lane < NH) {
    float x = myv + LB[lane];
    float sg = 1.f / (1.f + expf(-x));
    int b = s >> 13, seq = s & 8191;
    E[((size_t)(b * NH + lane) << 13) + seq] = sg * (1.f / 4096.f);
  }
}

// ---- kernel 3: eta writer: out[4][bh][p][k] = E[bh][srcchunk(p)*64 + k] ----
__global__ void k_eta(const float* __restrict__ E, float* __restrict__ out) {
  int gid = blockIdx.x * 256 + threadIdx.x;  // 4,194,304 threads (x16 f32 each... x4)
  int row = gid >> 4, kq = gid & 15;
  int bh = row >> 13, p = row & 8191;
  int q = p >> 11, r = p & 2047;
  int seq = (r < 64) ? ((q << 6) + r) : (192 + q * 1984 + r);
  int n = seq >> 6;
  f32x4 v = *(const f32x4*)(E + ((size_t)bh << 13) + (n << 6) + (kq << 2));
  *(f32x4*)(out + 4 * OUT_T + ((size_t)row << 6) + (kq << 2)) = v;
}

// ---- kernel 2: main fused GEMM + epilogue + permuted scatter ----
// block: 512 thr (8 waves, 2x4), tile 128 tokens x 256 cols (head h: q|k|v|u)
__global__ __launch_bounds__(512) void k_main(
    const float* __restrict__ X, const float* __restrict__ FC,
    const u16* __restrict__ WT,
    const float* __restrict__ qb, const float* __restrict__ kb,
    const float* __restrict__ vb, const float* __restrict__ ub,
    const float* __restrict__ tw, const float* __restrict__ tb,
    float* __restrict__ out) {
  __shared__ __align__(16) char smem[66560];
  u16* As = (u16*)smem;             // [128][64] bf16, XOR-swizzled 16B chunks
  u16* Bs = (u16*)(smem + 16384);   // [256][64] bf16, pre-swizzled content
  float* Cs = (float*)smem;         // [64][260] f32 epilogue slab (aliases)

  const int tid = threadIdx.x;
  const int lane = tid & 63;
  const int wid = tid >> 6;
  const int wm = wid >> 2, wn = wid & 3;
  const int bid = blockIdx.x;
  const int h = bid & 15;
  const int s0 = (bid >> 4) << 7;
  const int l15 = lane & 15, lg = lane >> 4;

  f32x4 acc[4][4];
  for (int i = 0; i < 4; ++i)
    for (int j = 0; j < 4; ++j)
      for (int r = 0; r < 4; ++r) acc[i][j][r] = 0.f;

  const float* bp = (wn == 0) ? qb : (wn == 1) ? kb : (wn == 2) ? vb : ub;
  float biasv[4];
  for (int fn = 0; fn < 4; ++fn) biasv[fn] = bp[h * 64 + fn * 16 + l15];

  // staging maps
  const int arow = tid >> 3, ac8 = tid & 7;
  const float* agp = X + (size_t)(s0 + arow) * ND + (ac8 << 3);
  u16* alp = As + arow * 64 + (((ac8 ^ arow) & 7) << 3);
  const int brow = tid >> 3, bc8 = tid & 7;

  int aoff[4], akey[4], boff[4], bkey[4];
  for (int f = 0; f < 4; ++f) {
    int ra = (wm << 6) + (f << 4) + l15;
    aoff[f] = ra << 6; akey[f] = ra & 7;
    int rb = (wn << 6) + (f << 4) + l15;
    boff[f] = rb << 6; bkey[f] = rb & 7;
  }

  for (int kt = 0; kt < 16; ++kt) {
    const int k0 = kt << 6;
    // A: 2 chunks of 8 f32 -> bf16
    const float4* p0 = (const float4*)(agp + k0);
    const float4* p1 = (const float4*)(agp + k0 + (size_t)64 * ND);
    float4 x0 = p0[0], x1 = p0[1];
    float4 y0 = p1[0], y1 = p1[1];
    // B: 4 chunks (one per weight), pre-swizzled bf16: pure linear copy
    short8v bvv[4];
    for (int it = 0; it < 4; ++it) {
      size_t g = (((size_t)(it * ND + h * 64 + brow)) << 10) + k0 + (bc8 << 3);
      bvv[it] = *(const short8v*)(WT + g);
    }
    *(short8v*)alp = pack8(x0, x1);
    *(short8v*)(alp + 64 * 64) = pack8(y0, y1);
    for (int it = 0; it < 4; ++it)
      *(short8v*)(Bs + ((it << 6) + brow) * 64 + (bc8 << 3)) = bvv[it];
    __syncthreads();
    for (int ks = 0; ks < 2; ++ks) {
      const int kc = (ks << 2) + lg;  // 16B-chunk index 0..7
      short8v af[4], bf[4];
      for (int f = 0; f < 4; ++f)
        af[f] = *(const short8v*)(As + aoff[f] + ((kc ^ akey[f]) << 3));
      for (int f = 0; f < 4; ++f)
        bf[f] = *(const short8v*)(Bs + boff[f] + ((kc ^ bkey[f]) << 3));
      for (int fm = 0; fm < 4; ++fm)
        for (int fn = 0; fn < 4; ++fn)
          acc[fm][fn] = __builtin_amdgcn_mfma_f32_16x16x32_bf16(
              af[fm], bf[fn], acc[fm][fn], 0, 0, 0);
    }
    __syncthreads();
  }

  // epilogue: two 64-token slabs
  for (int slab = 0; slab < 2; ++slab) {
    if (wm == slab) {
      for (int fm = 0; fm < 4; ++fm)
        for (int fn = 0; fn < 4; ++fn)
          for (int rr = 0; rr < 4; ++rr) {
            int row = (fm << 4) + (lg << 2) + rr;       // C/D: col=lane&15, row=(lane>>4)*4+reg
            int col = (wn << 6) + (fn << 4) + l15;
            Cs[row * 260 + col] = acc[fm][fn][rr] + biasv[fn];
          }
    }
    __syncthreads();
    if (wm == slab) {
      int gtid = tid & 255;
      int tloc = gtid >> 2, t4 = gtid & 3;
      int stok = s0 + (slab << 6) + tloc;
      int b = stok >> 13, seq = stok & 8191;
      const float* crow = Cs + tloc * 260;
      int dbase = t4 << 4;
      float fc[16];
      {
        const f32x4* fp = (const f32x4*)(FC + ((size_t)seq << 6) + dbase);
        for (int i = 0; i < 4; ++i) {
          f32x4 t = fp[i];
          fc[4*i] = t[0]; fc[4*i+1] = t[1]; fc[4*i+2] = t[2]; fc[4*i+3] = t[3];
        }
      }
      float sq = 0.f, sk = 0.f, su = 0.f;
      for (int j = 0; j < 16; ++j) {
        float a = crow[dbase + j], b2 = crow[64 + dbase + j], c = crow[192 + dbase + j];
        sq += a * a; sk += b2 * b2; su += c * c;
      }
      sq += __shfl_xor(sq, 1); sq += __shfl_xor(sq, 2);
      sk += __shfl_xor(sk, 1); sk += __shfl_xor(sk, 2);
      su += __shfl_xor(su, 1); su += __shfl_xor(su, 2);
      float qi = 1.f / fmaxf(sqrtf(sq), 1e-12f);
      float ki = 1.f / fmaxf(sqrtf(sk), 1e-12f);
      float ui = 1.f / fmaxf(sqrtf(su), 1e-12f);
      // inverse interleave: source seq -> output position p
      int p;
      if (seq < 256) p = ((seq >> 6) << 11) + (seq & 63);
      else { int v = seq - 256; int qc = v / 1984; p = (qc << 11) + 64 + (v - qc * 1984); }
      float* po = out + ((((size_t)(b * NH + h) << 13) + p) << 6) + dbase;
      // K: l2norm + rope
      float kr[16];
      for (int jj = 0; jj < 8; ++jj) {
        float xa = crow[64 + dbase + 2*jj] * ki, xb = crow[64 + dbase + 2*jj + 1] * ki;
        float c = fc[2*jj], s = fc[2*jj+1];
        kr[2*jj]     = xa * c - xb * s;
        kr[2*jj + 1] = xa * s + xb * c;
      }
      st16(po + OUT_T, kr);
      // V: layernorm(ddof=1) over (v - kr), then *tw + tb + kr
      float sd = 0.f, sdd = 0.f, df[16];
      for (int j = 0; j < 16; ++j) {
        df[j] = crow[128 + dbase + j] - kr[j];
        sd += df[j]; sdd += df[j] * df[j];
      }
      sd += __shfl_xor(sd, 1); sd += __shfl_xor(sd, 2);
      sdd += __shfl_xor(sdd, 1); sdd += __shfl_xor(sdd, 2);
      float mean = sd * (1.f / 64.f);
      float var = (sdd - sd * sd * (1.f / 64.f)) * (1.f / 63.f);
      float istd = 1.f / (sqrtf(fmaxf(var, 0.f)) + 1e-8f);
      for (int j = 0; j < 16; ++j) {
        int d = dbase + j;
        df[j] = tw[h * 64 + d] * ((df[j] - mean) * istd) + tb[h * 64 + d] + kr[j];
      }
      st16(po + 2 * OUT_T, df);
      // Q: l2norm + rope
      float qr[16];
      for (int jj = 0; jj < 8; ++jj) {
        float xa = crow[dbase + 2*jj] * qi, xb = crow[dbase + 2*jj + 1] * qi;
        float c = fc[2*jj], s = fc[2*jj+1];
        qr[2*jj]     = xa * c - xb * s;
        qr[2*jj + 1] = xa * s + xb * c;
      }
      st16(po, qr);
      // U: l2norm + rope
      for (int jj = 0; jj < 8; ++jj) {
        float xa = crow[192 + dbase + 2*jj] * ui, xb = crow[192 + dbase + 2*jj + 1] * ui;
        float c = fc[2*jj], s = fc[2*jj+1];
        qr[2*jj]     = xa * c - xb * s;
        qr[2*jj + 1] = xa * s + xb * c;
      }
      st16(po + 3 * OUT_T, qr);
    }
    __syncthreads();
  }
}

extern "C" void kernel_launch(void* const* d_in, const int* in_sizes, int n_in,
                              void* d_out, int out_size, void* d_ws, size_t ws_size,
                              hipStream_t stream) {
  const float* X  = (const float*)d_in[0];
  const float* FC = (const float*)d_in[1];
  const float* wq = (const float*)d_in[2];
  const float* qb = (const float*)d_in[3];
  const float* wk = (const float*)d_in[4];
  const float* kb = (const float*)d_in[5];
  const float* wv = (const float*)d_in[6];
  const float* vb = (const float*)d_in[7];
  const float* wu = (const float*)d_in[8];
  const float* ub = (const float*)d_in[9];
  const float* tw = (const float*)d_in[10];
  const float* tb = (const float*)d_in[11];
  const float* lw = (const float*)d_in[12];
  const float* lb = (const float*)d_in[13];
  float* out = (float*)d_out;
  u16* WT = (u16*)d_ws;                           // 8 MB: 4x1024x1024 bf16
  float* E = (float*)((char*)d_ws + (8u << 20));  // 1 MB: 2*16*8192 f32

  hipLaunchKernelGGL(k_wt, dim3(1024), dim3(256), 0, stream, wq, wk, wv, wu, WT);
  hipLaunchKernelGGL(k_lr, dim3(4096), dim3(256), 0, stream, X, lw, lb, E);
  hipLaunchKernelGGL(k_main, dim3(2048), dim3(512), 0, stream,
                     X, FC, WT, qb, kb, vb, ub, tw, tb, out);
  hipLaunchKernelGGL(k_eta, dim3(16384), dim3(256), 0, stream, E, out);
}

// Round 2
// 356.383 us; speedup vs baseline: 1.0009x; 1.0009x over previous
//
#include <hip/hip_runtime.h>

typedef unsigned int u32;
typedef unsigned short u16;
typedef short short8v __attribute__((ext_vector_type(8)));
typedef float f32x4 __attribute__((ext_vector_type(4)));

#define ND 1024
#define NH 16
#define OUT_T ((size_t)16777216)  // 2*16*8192*64 elements per stacked tensor

__device__ __forceinline__ u16 f2bf(float f) {
  u32 u = __float_as_uint(f);
  u32 r = u + 0x7fffu + ((u >> 16) & 1u);
  return (u16)(r >> 16);
}

__device__ __forceinline__ short8v pack8(float4 a, float4 b) {
  short8v v;
  v[0] = (short)f2bf(a.x); v[1] = (short)f2bf(a.y);
  v[2] = (short)f2bf(a.z); v[3] = (short)f2bf(a.w);
  v[4] = (short)f2bf(b.x); v[5] = (short)f2bf(b.y);
  v[6] = (short)f2bf(b.z); v[7] = (short)f2bf(b.w);
  return v;
}

__device__ __forceinline__ void st16(float* p, const float* v) {
  for (int i = 0; i < 4; ++i) {
    f32x4 t; t[0] = v[4*i]; t[1] = v[4*i+1]; t[2] = v[4*i+2]; t[3] = v[4*i+3];
    *(f32x4*)(p + 4*i) = t;
  }
}

__device__ __forceinline__ void gload16(const void* g, void* l) {
  __builtin_amdgcn_global_load_lds((const __attribute__((address_space(1))) void*)g,
                                   (__attribute__((address_space(3))) void*)l, 16, 0, 0);
}

// ---- kernel 0: weights -> WT[w][c][kswz] bf16, transposed + swizzled ----
// stored position of original 16B k-chunk kc (8 bf16) is kc ^ (c&7)
__global__ void k_wt(const float* __restrict__ w0, const float* __restrict__ w1,
                     const float* __restrict__ w2, const float* __restrict__ w3,
                     u16* __restrict__ WT) {
  __shared__ float T[64][65];
  int bid = blockIdx.x;
  int w = bid >> 8;
  int tk = (bid >> 4) & 15, tc = bid & 15;
  const float* W = w == 0 ? w0 : w == 1 ? w1 : w == 2 ? w2 : w3;
  int k0 = tk << 6, c0 = tc << 6;
  int tid = threadIdx.x;
  for (int it = 0; it < 16; ++it) {
    int idx = it * 256 + tid;
    int kk = idx >> 6, cc = idx & 63;
    T[kk][cc] = W[(size_t)(k0 + kk) * ND + c0 + cc];
  }
  __syncthreads();
  for (int it = 0; it < 2; ++it) {
    int ci = it * 256 + tid;
    int cc = ci >> 3, k8 = ci & 7;
    int c = c0 + cc;
    short8v v;
    for (int j = 0; j < 8; ++j) v[j] = (short)f2bf(T[k8 * 8 + j][cc]);
    size_t off = ((size_t)(w * ND + c) << 10) + k0 + (((k8 ^ c) & 7) << 3);
    *(short8v*)(WT + off) = v;
  }
}

// ---- kernel 0b: X f32 -> bf16 ----
__global__ void k_xbf(const float* __restrict__ X, u16* __restrict__ Xb) {
  size_t i = ((size_t)blockIdx.x * 256 + threadIdx.x) * 8;
  float4 a = *(const float4*)(X + i), b = *(const float4*)(X + i + 4);
  *(short8v*)(Xb + i) = pack8(a, b);
}

// ---- kernel 1: lr projection -> E[b*16+h][seq] = sigmoid(x.lrw_h + lrb_h)/4096 ----
__global__ void k_lr(const float* __restrict__ X, const float* __restrict__ LW,
                     const float* __restrict__ LB, float* __restrict__ E) {
  int tid = threadIdx.x;
  int lane = tid & 63;
  int s = blockIdx.x * 4 + (tid >> 6);
  float xr[16];
  const float* xp = X + (size_t)s * ND + lane;
  for (int i = 0; i < 16; ++i) xr[i] = xp[i * 64];
  float myv = 0.f;
  for (int h = 0; h < NH; ++h) {
    const float* wp = LW + h * ND + lane;
    float acc = 0.f;
    for (int i = 0; i < 16; ++i) acc += xr[i] * wp[i * 64];
    for (int off = 32; off; off >>= 1) acc += __shfl_xor(acc, off);
    if (lane == h) myv = acc;
  }
  if (lane < NH) {
    float x = myv + LB[lane];
    float sg = 1.f / (1.f + expf(-x));
    int b = s >> 13, seq = s & 8191;
    E[((size_t)(b * NH + lane) << 13) + seq] = sg * (1.f / 4096.f);
  }
}

// ---- kernel 3: eta writer: out[4][bh][p][k] = E[bh][srcchunk(p)*64 + k] ----
__global__ void k_eta(const float* __restrict__ E, float* __restrict__ out) {
  int gid = blockIdx.x * 256 + threadIdx.x;
  int row = gid >> 4, kq = gid & 15;
  int bh = row >> 13, p = row & 8191;
  int q = p >> 11, r = p & 2047;
  int seq = (r < 64) ? ((q << 6) + r) : (192 + q * 1984 + r);
  int n = seq >> 6;
  f32x4 v = *(const f32x4*)(E + ((size_t)bh << 13) + (n << 6) + (kq << 2));
  *(f32x4*)(out + 4 * OUT_T + ((size_t)row << 6) + (kq << 2)) = v;
}

// ---- kernel 2: main fused GEMM + epilogue + permuted scatter ----
// block: 512 thr (8 waves, 2x4), tile 128 tokens x 256 cols (head h: q|k|v|u)
__global__ __launch_bounds__(512) void k_main(
    const u16* __restrict__ Xb, const float* __restrict__ FC,
    const u16* __restrict__ WT,
    const float* __restrict__ qb, const float* __restrict__ kb,
    const float* __restrict__ vb, const float* __restrict__ ub,
    const float* __restrict__ tw, const float* __restrict__ tb,
    float* __restrict__ out) {
  __shared__ __align__(16) char smem[66560];
  u16* As = (u16*)smem;             // [128][64] bf16, XOR-swizzled 16B chunks
  u16* Bs = (u16*)(smem + 16384);   // [256][64] bf16, content pre-swizzled
  float* Cs = (float*)smem;         // [64][260] f32 epilogue slab (aliases)

  const int tid = threadIdx.x;
  const int lane = tid & 63;
  const int wid = tid >> 6;
  const int wm = wid >> 2, wn = wid & 3;
  // XCD-chunked swizzle: grid 2048 = 8 * 256
  const int bid = (blockIdx.x & 7) * 256 + (blockIdx.x >> 3);
  const int h = bid & 15;
  const int s0 = (bid >> 4) << 7;
  const int l15 = lane & 15, lg = lane >> 4;

  f32x4 acc[4][4];
  for (int i = 0; i < 4; ++i)
    for (int j = 0; j < 4; ++j)
      for (int r = 0; r < 4; ++r) acc[i][j][r] = 0.f;

  const float* bp = (wn == 0) ? qb : (wn == 1) ? kb : (wn == 2) ? vb : ub;
  float biasv[4];
  for (int fn = 0; fn < 4; ++fn) biasv[fn] = bp[h * 64 + fn * 16 + l15];

  // ---- staging address setup (global_load_lds, width 16) ----
  // A: wave w covers rows [w*16, w*16+16), two 1KB wave-loads of 8 rows.
  //    LDS linear; swizzle folded into per-lane global source chunk.
  const int arow0 = wid * 16 + (lane >> 3);
  const int achunk = (lane & 7) ^ (arow0 & 7);
  const u16* asrc = Xb + (size_t)(s0 + arow0) * ND + (achunk << 3);
  u16* aldst = As + wid * 1024;  // wave-uniform
  // B: wave w covers rows [w*32, w*32+32), four 1KB wave-loads.
  //    WT content pre-swizzled -> fully linear copy.
  const int brow0 = wid * 32 + (lane >> 3);        // j adds 8
  const int bit0 = brow0 >> 6;                     // constant within wave
  const u16* bsrc = WT + (((size_t)(bit0 * ND + h * 64 + (brow0 & 63))) << 10) + ((lane & 7) << 3);
  u16* bldst = Bs + wid * 2048;  // wave-uniform

  int aoff[4], akey[4], boff[4], bkey[4];
  for (int f = 0; f < 4; ++f) {
    int ra = (wm << 6) + (f << 4) + l15;
    aoff[f] = ra << 6; akey[f] = ra & 7;
    int rb = (wn << 6) + (f << 4) + l15;
    boff[f] = rb << 6; bkey[f] = rb & 7;
  }

  for (int kt = 0; kt < 16; ++kt) {
    const int k0 = kt << 6;
    gload16(asrc + k0, aldst);
    gload16(asrc + k0 + 8 * ND, aldst + 512);
    for (int j = 0; j < 4; ++j)
      gload16(bsrc + k0 + j * 8192, bldst + j * 512);
    __syncthreads();   // drains vmcnt(0): staged tile visible
    for (int ks = 0; ks < 2; ++ks) {
      const int kc = (ks << 2) + lg;  // 16B-chunk index 0..7
      short8v af[4], bf[4];
      for (int f = 0; f < 4; ++f)
        af[f] = *(const short8v*)(As + aoff[f] + ((kc ^ akey[f]) << 3));
      for (int f = 0; f < 4; ++f)
        bf[f] = *(const short8v*)(Bs + boff[f] + ((kc ^ bkey[f]) << 3));
      for (int fm = 0; fm < 4; ++fm)
        for (int fn = 0; fn < 4; ++fn)
          acc[fm][fn] = __builtin_amdgcn_mfma_f32_16x16x32_bf16(
              af[fm], bf[fn], acc[fm][fn], 0, 0, 0);
    }
    __syncthreads();   // all waves done reading before next-tile overwrite
  }

  // epilogue: two 64-token slabs
  for (int slab = 0; slab < 2; ++slab) {
    if (wm == slab) {
      for (int fm = 0; fm < 4; ++fm)
        for (int fn = 0; fn < 4; ++fn)
          for (int rr = 0; rr < 4; ++rr) {
            int row = (fm << 4) + (lg << 2) + rr;   // C/D: col=lane&15, row=(lane>>4)*4+reg
            int col = (wn << 6) + (fn << 4) + l15;
            Cs[row * 260 + col] = acc[fm][fn][rr] + biasv[fn];
          }
    }
    __syncthreads();
    if (wm == slab) {
      int gtid = tid & 255;
      int tloc = gtid >> 2, t4 = gtid & 3;
      int stok = s0 + (slab << 6) + tloc;
      int b = stok >> 13, seq = stok & 8191;
      const float* crow = Cs + tloc * 260;
      int dbase = t4 << 4;
      float fc[16];
      {
        const f32x4* fp = (const f32x4*)(FC + ((size_t)seq << 6) + dbase);
        for (int i = 0; i < 4; ++i) {
          f32x4 t = fp[i];
          fc[4*i] = t[0]; fc[4*i+1] = t[1]; fc[4*i+2] = t[2]; fc[4*i+3] = t[3];
        }
      }
      float sq = 0.f, sk = 0.f, su = 0.f;
      for (int j = 0; j < 16; ++j) {
        float a = crow[dbase + j], b2 = crow[64 + dbase + j], c = crow[192 + dbase + j];
        sq += a * a; sk += b2 * b2; su += c * c;
      }
      sq += __shfl_xor(sq, 1); sq += __shfl_xor(sq, 2);
      sk += __shfl_xor(sk, 1); sk += __shfl_xor(sk, 2);
      su += __shfl_xor(su, 1); su += __shfl_xor(su, 2);
      float qi = 1.f / fmaxf(sqrtf(sq), 1e-12f);
      float ki = 1.f / fmaxf(sqrtf(sk), 1e-12f);
      float ui = 1.f / fmaxf(sqrtf(su), 1e-12f);
      // inverse interleave: source seq -> output position p
      int p;
      if (seq < 256) p = ((seq >> 6) << 11) + (seq & 63);
      else { int v = seq - 256; int qc = v / 1984; p = (qc << 11) + 64 + (v - qc * 1984); }
      float* po = out + ((((size_t)(b * NH + h) << 13) + p) << 6) + dbase;
      // K: l2norm + rope
      float kr[16];
      for (int jj = 0; jj < 8; ++jj) {
        float xa = crow[64 + dbase + 2*jj] * ki, xb = crow[64 + dbase + 2*jj + 1] * ki;
        float c = fc[2*jj], s = fc[2*jj+1];
        kr[2*jj]     = xa * c - xb * s;
        kr[2*jj + 1] = xa * s + xb * c;
      }
      st16(po + OUT_T, kr);
      // V: layernorm(ddof=1) over (v - kr), then *tw + tb + kr
      float sd = 0.f, sdd = 0.f, df[16];
      for (int j = 0; j < 16; ++j) {
        df[j] = crow[128 + dbase + j] - kr[j];
        sd += df[j]; sdd += df[j] * df[j];
      }
      sd += __shfl_xor(sd, 1); sd += __shfl_xor(sd, 2);
      sdd += __shfl_xor(sdd, 1); sdd += __shfl_xor(sdd, 2);
      float mean = sd * (1.f / 64.f);
      float var = (sdd - sd * sd * (1.f / 64.f)) * (1.f / 63.f);
      float istd = 1.f / (sqrtf(fmaxf(var, 0.f)) + 1e-8f);
      for (int j = 0; j < 16; ++j) {
        int d = dbase + j;
        df[j] = tw[h * 64 + d] * ((df[j] - mean) * istd) + tb[h * 64 + d] + kr[j];
      }
      st16(po + 2 * OUT_T, df);
      // Q: l2norm + rope
      float qr[16];
      for (int jj = 0; jj < 8; ++jj) {
        float xa = crow[dbase + 2*jj] * qi, xb = crow[dbase + 2*jj + 1] * qi;
        float c = fc[2*jj], s = fc[2*jj+1];
        qr[2*jj]     = xa * c - xb * s;
        qr[2*jj + 1] = xa * s + xb * c;
      }
      st16(po, qr);
      // U: l2norm + rope
      for (int jj = 0; jj < 8; ++jj) {
        float xa = crow[192 + dbase + 2*jj] * ui, xb = crow[192 + dbase + 2*jj + 1] * ui;
        float c = fc[2*jj], s = fc[2*jj+1];
        qr[2*jj]     = xa * c - xb * s;
        qr[2*jj + 1] = xa * s + xb * c;
      }
      st16(po + 3 * OUT_T, qr);
    }
    __syncthreads();
  }
}

extern "C" void kernel_launch(void* const* d_in, const int* in_sizes, int n_in,
                              void* d_out, int out_size, void* d_ws, size_t ws_size,
                              hipStream_t stream) {
  const float* X  = (const float*)d_in[0];
  const float* FC = (const float*)d_in[1];
  const float* wq = (const float*)d_in[2];
  const float* qb = (const float*)d_in[3];
  const float* wk = (const float*)d_in[4];
  const float* kb = (const float*)d_in[5];
  const float* wv = (const float*)d_in[6];
  const float* vb = (const float*)d_in[7];
  const float* wu = (const float*)d_in[8];
  const float* ub = (const float*)d_in[9];
  const float* tw = (const float*)d_in[10];
  const float* tb = (const float*)d_in[11];
  const float* lw = (const float*)d_in[12];
  const float* lb = (const float*)d_in[13];
  float* out = (float*)d_out;
  u16* WT = (u16*)d_ws;                             // 8 MB: 4x1024x1024 bf16
  float* E = (float*)((char*)d_ws + (8u << 20));    // 1 MB: 2*16*8192 f32
  u16* Xb = (u16*)((char*)d_ws + (9u << 20));       // 32 MB: 16384x1024 bf16

  hipLaunchKernelGGL(k_wt, dim3(1024), dim3(256), 0, stream, wq, wk, wv, wu, WT);
  hipLaunchKernelGGL(k_xbf, dim3(8192), dim3(256), 0, stream, X, Xb);
  hipLaunchKernelGGL(k_lr, dim3(4096), dim3(256), 0, stream, X, lw, lb, E);
  hipLaunchKernelGGL(k_main, dim3(2048), dim3(512), 0, stream,
                     Xb, FC, WT, qb, kb, vb, ub, tw, tb, out);
  hipLaunchKernelGGL(k_eta, dim3(16384), dim3(256), 0, stream, E, out);
}

// Round 3
// 297.755 us; speedup vs baseline: 1.1979x; 1.1969x over previous
//
#include <hip/hip_runtime.h>

typedef unsigned int u32;
typedef unsigned short u16;
typedef short short8v __attribute__((ext_vector_type(8)));
typedef float f32x4 __attribute__((ext_vector_type(4)));

#define ND 1024
#define NH 16
#define OUT_T ((size_t)16777216)  // 2*16*8192*64 elements per stacked tensor

__device__ __forceinline__ u16 f2bf(float f) {
  u32 u = __float_as_uint(f);
  u32 r = u + 0x7fffu + ((u >> 16) & 1u);
  return (u16)(r >> 16);
}

__device__ __forceinline__ float bf2f(u16 b) {
  return __uint_as_float(((u32)b) << 16);
}

__device__ __forceinline__ short8v pack8(float4 a, float4 b) {
  short8v v;
  v[0] = (short)f2bf(a.x); v[1] = (short)f2bf(a.y);
  v[2] = (short)f2bf(a.z); v[3] = (short)f2bf(a.w);
  v[4] = (short)f2bf(b.x); v[5] = (short)f2bf(b.y);
  v[6] = (short)f2bf(b.z); v[7] = (short)f2bf(b.w);
  return v;
}

__device__ __forceinline__ void st8(float* p, const float* v) {
  for (int i = 0; i < 2; ++i) {
    f32x4 t; t[0] = v[4*i]; t[1] = v[4*i+1]; t[2] = v[4*i+2]; t[3] = v[4*i+3];
    *(f32x4*)(p + 4*i) = t;
  }
}

__device__ __forceinline__ void gload16(const void* g, void* l) {
  __builtin_amdgcn_global_load_lds((const __attribute__((address_space(1))) void*)g,
                                   (__attribute__((address_space(3))) void*)l, 16, 0, 0);
}

// ---- kernel 0: weights -> WT[w][c][kswz] bf16, transposed + swizzled ----
// stored position of original 16B k-chunk kc (8 bf16) is kc ^ (c&7)
__global__ void k_wt(const float* __restrict__ w0, const float* __restrict__ w1,
                     const float* __restrict__ w2, const float* __restrict__ w3,
                     u16* __restrict__ WT) {
  __shared__ float T[64][65];
  int bid = blockIdx.x;
  int w = bid >> 8;
  int tk = (bid >> 4) & 15, tc = bid & 15;
  const float* W = w == 0 ? w0 : w == 1 ? w1 : w == 2 ? w2 : w3;
  int k0 = tk << 6, c0 = tc << 6;
  int tid = threadIdx.x;
  for (int it = 0; it < 16; ++it) {
    int idx = it * 256 + tid;
    int kk = idx >> 6, cc = idx & 63;
    T[kk][cc] = W[(size_t)(k0 + kk) * ND + c0 + cc];
  }
  __syncthreads();
  for (int it = 0; it < 2; ++it) {
    int ci = it * 256 + tid;
    int cc = ci >> 3, k8 = ci & 7;
    int c = c0 + cc;
    short8v v;
    for (int j = 0; j < 8; ++j) v[j] = (short)f2bf(T[k8 * 8 + j][cc]);
    size_t off = ((size_t)(w * ND + c) << 10) + k0 + (((k8 ^ c) & 7) << 3);
    *(short8v*)(WT + off) = v;
  }
}

// ---- kernel 0b: X f32 -> bf16 ----
__global__ void k_xbf(const float* __restrict__ X, u16* __restrict__ Xb) {
  size_t i = ((size_t)blockIdx.x * 256 + threadIdx.x) * 8;
  float4 a = *(const float4*)(X + i), b = *(const float4*)(X + i + 4);
  *(short8v*)(Xb + i) = pack8(a, b);
}

// ---- kernel 1: lr projection (reads bf16 Xb) -> E[b*16+h][seq] ----
__global__ void k_lr(const u16* __restrict__ Xb, const float* __restrict__ LW,
                     const float* __restrict__ LB, float* __restrict__ E) {
  int tid = threadIdx.x;
  int lane = tid & 63;
  int s = blockIdx.x * 4 + (tid >> 6);
  float xr[16];
  const u16* xp = Xb + (size_t)s * ND + lane;
  for (int i = 0; i < 16; ++i) xr[i] = bf2f(xp[i * 64]);
  float myv = 0.f;
  for (int h = 0; h < NH; ++h) {
    const float* wp = LW + h * ND + lane;
    float acc = 0.f;
    for (int i = 0; i < 16; ++i) acc += xr[i] * wp[i * 64];
    for (int off = 32; off; off >>= 1) acc += __shfl_xor(acc, off);
    if (lane == h) myv = acc;
  }
  if (lane < NH) {
    float x = myv + LB[lane];
    float sg = 1.f / (1.f + expf(-x));
    int b = s >> 13, seq = s & 8191;
    E[((size_t)(b * NH + lane) << 13) + seq] = sg * (1.f / 4096.f);
  }
}

// ---- kernel 3: eta writer: out[4][bh][p][k] = E[bh][srcchunk(p)*64 + k] ----
__global__ void k_eta(const float* __restrict__ E, float* __restrict__ out) {
  int gid = blockIdx.x * 256 + threadIdx.x;
  int row = gid >> 4, kq = gid & 15;
  int bh = row >> 13, p = row & 8191;
  int q = p >> 11, r = p & 2047;
  int seq = (r < 64) ? ((q << 6) + r) : (192 + q * 1984 + r);
  int n = seq >> 6;
  f32x4 v = *(const f32x4*)(E + ((size_t)bh << 13) + (n << 6) + (kq << 2));
  *(f32x4*)(out + 4 * OUT_T + ((size_t)row << 6) + (kq << 2)) = v;
}

// ---- kernel 2: main fused GEMM + epilogue + permuted scatter ----
// block: 256 thr (4 waves), tile 64 tokens x 256 cols (head h: q|k|v|u).
// Wave wn owns the full 64 rows x 64 cols of tensor wn -> acc 4x4 frags.
__global__ __launch_bounds__(256, 3) void k_main(
    const u16* __restrict__ Xb, const float* __restrict__ FC,
    const u16* __restrict__ WT,
    const float* __restrict__ qb, const float* __restrict__ kb,
    const float* __restrict__ vb, const float* __restrict__ ub,
    const float* __restrict__ tw, const float* __restrict__ tb,
    float* __restrict__ out) {
  __shared__ __align__(16) char smem[40960];
  u16* As = (u16*)smem;             // [64][64] bf16, XOR-swizzled 16B chunks (8KB)
  u16* Bs = (u16*)(smem + 8192);    // [256][64] bf16, content pre-swizzled (32KB)
  float* Cs = (float*)smem;         // [32][260] f32 epilogue half-slab (33.3KB, aliases)

  const int tid = threadIdx.x;
  const int lane = tid & 63;
  const int wn = tid >> 6;          // wave id == tensor id (0=q,1=k,2=v,3=u)
  // XCD-chunked swizzle: grid 4096 = 8 * 512
  const int bid = (blockIdx.x & 7) * 512 + (blockIdx.x >> 3);
  const int h = bid & 15;
  const int s0 = (bid >> 4) << 6;
  const int l15 = lane & 15, lg = lane >> 4;

  f32x4 acc[4][4];
  for (int i = 0; i < 4; ++i)
    for (int j = 0; j < 4; ++j)
      for (int r = 0; r < 4; ++r) acc[i][j][r] = 0.f;

  const float* bp = (wn == 0) ? qb : (wn == 1) ? kb : (wn == 2) ? vb : ub;
  float biasv[4];
  for (int fn = 0; fn < 4; ++fn) biasv[fn] = bp[h * 64 + fn * 16 + l15];

  // ---- staging (global_load_lds width 16), LDS linear dest ----
  // A: wave wn stages rows [wn*16, wn*16+16): two 1KB wave-loads.
  const int arow0 = wn * 16 + (lane >> 3);
  const u16* asrc = Xb + (size_t)(s0 + arow0) * ND + ((((lane & 7) ^ arow0) & 7) << 3);
  u16* aldst = As + wn * 1024;  // wave-uniform
  // B: wave wn stages weight wn's 64 cols: eight 1KB wave-loads (pre-swizzled -> linear).
  const u16* bsrc = WT + (((size_t)(wn * ND + h * 64 + (lane >> 3))) << 10) + ((lane & 7) << 3);
  u16* bldst = Bs + wn * 4096;  // wave-uniform

  int aoff[4], akey[4], boff[4], bkey[4];
  for (int f = 0; f < 4; ++f) {
    int ra = (f << 4) + l15;
    aoff[f] = ra << 6; akey[f] = ra & 7;
    int rb = (wn << 6) + (f << 4) + l15;
    boff[f] = rb << 6; bkey[f] = rb & 7;
  }

  for (int kt = 0; kt < 16; ++kt) {
    const int k0 = kt << 6;
    gload16(asrc + k0, aldst);
    gload16(asrc + k0 + 8 * ND, aldst + 512);
    for (int j = 0; j < 8; ++j)
      gload16(bsrc + k0 + j * 8192, bldst + j * 512);
    __syncthreads();
    for (int ks = 0; ks < 2; ++ks) {
      const int kc = (ks << 2) + lg;  // 16B-chunk index 0..7
      short8v af[4], bf[4];
      for (int f = 0; f < 4; ++f)
        af[f] = *(const short8v*)(As + aoff[f] + ((kc ^ akey[f]) << 3));
      for (int f = 0; f < 4; ++f)
        bf[f] = *(const short8v*)(Bs + boff[f] + ((kc ^ bkey[f]) << 3));
      for (int fm = 0; fm < 4; ++fm)
        for (int fn = 0; fn < 4; ++fn)
          acc[fm][fn] = __builtin_amdgcn_mfma_f32_16x16x32_bf16(
              af[fm], bf[fn], acc[fm][fn], 0, 0, 0);
    }
    __syncthreads();
  }

  // epilogue: two 32-token phases through Cs (all 256 threads active)
  for (int ph = 0; ph < 2; ++ph) {
    for (int fm = ph * 2; fm < ph * 2 + 2; ++fm)
      for (int fn = 0; fn < 4; ++fn)
        for (int rr = 0; rr < 4; ++rr) {
          int row = (fm << 4) + (lg << 2) + rr;   // C/D: col=lane&15, row=(lane>>4)*4+reg
          int rl = row - ph * 32;
          int col = (wn << 6) + (fn << 4) + l15;
          Cs[rl * 260 + col] = acc[fm][fn][rr] + biasv[fn];
        }
    __syncthreads();
    {
      int tloc = tid >> 3, o = tid & 7;
      int dbase = o << 3;
      int stok = s0 + (ph << 5) + tloc;
      int b = stok >> 13, seq = stok & 8191;
      const float* crow = Cs + tloc * 260;
      float fc[8];
      {
        const f32x4* fp = (const f32x4*)(FC + ((size_t)seq << 6) + dbase);
        f32x4 t0 = fp[0], t1 = fp[1];
        fc[0] = t0[0]; fc[1] = t0[1]; fc[2] = t0[2]; fc[3] = t0[3];
        fc[4] = t1[0]; fc[5] = t1[1]; fc[6] = t1[2]; fc[7] = t1[3];
      }
      float sq = 0.f, sk = 0.f, su = 0.f;
      for (int j = 0; j < 8; ++j) {
        float a = crow[dbase + j], b2 = crow[64 + dbase + j], c = crow[192 + dbase + j];
        sq += a * a; sk += b2 * b2; su += c * c;
      }
      sq += __shfl_xor(sq, 1); sq += __shfl_xor(sq, 2); sq += __shfl_xor(sq, 4);
      sk += __shfl_xor(sk, 1); sk += __shfl_xor(sk, 2); sk += __shfl_xor(sk, 4);
      su += __shfl_xor(su, 1); su += __shfl_xor(su, 2); su += __shfl_xor(su, 4);
      float qi = 1.f / fmaxf(sqrtf(sq), 1e-12f);
      float ki = 1.f / fmaxf(sqrtf(sk), 1e-12f);
      float ui = 1.f / fmaxf(sqrtf(su), 1e-12f);
      // inverse interleave: source seq -> output position p
      int p;
      if (seq < 256) p = ((seq >> 6) << 11) + (seq & 63);
      else { int v = seq - 256; int qc = v / 1984; p = (qc << 11) + 64 + (v - qc * 1984); }
      float* po = out + ((((size_t)(b * NH + h) << 13) + p) << 6) + dbase;
      // K: l2norm + rope
      float kr[8];
      for (int jj = 0; jj < 4; ++jj) {
        float xa = crow[64 + dbase + 2*jj] * ki, xb = crow[64 + dbase + 2*jj + 1] * ki;
        float c = fc[2*jj], s = fc[2*jj+1];
        kr[2*jj]     = xa * c - xb * s;
        kr[2*jj + 1] = xa * s + xb * c;
      }
      st8(po + OUT_T, kr);
      // V: layernorm(ddof=1) over (v - kr), then *tw + tb + kr
      float sd = 0.f, sdd = 0.f, df[8];
      for (int j = 0; j < 8; ++j) {
        df[j] = crow[128 + dbase + j] - kr[j];
        sd += df[j]; sdd += df[j] * df[j];
      }
      sd += __shfl_xor(sd, 1); sd += __shfl_xor(sd, 2); sd += __shfl_xor(sd, 4);
      sdd += __shfl_xor(sdd, 1); sdd += __shfl_xor(sdd, 2); sdd += __shfl_xor(sdd, 4);
      float mean = sd * (1.f / 64.f);
      float var = (sdd - sd * sd * (1.f / 64.f)) * (1.f / 63.f);
      float istd = 1.f / (sqrtf(fmaxf(var, 0.f)) + 1e-8f);
      for (int j = 0; j < 8; ++j) {
        int d = dbase + j;
        df[j] = tw[h * 64 + d] * ((df[j] - mean) * istd) + tb[h * 64 + d] + kr[j];
      }
      st8(po + 2 * OUT_T, df);
      // Q: l2norm + rope
      float qr[8];
      for (int jj = 0; jj < 4; ++jj) {
        float xa = crow[dbase + 2*jj] * qi, xb = crow[dbase + 2*jj + 1] * qi;
        float c = fc[2*jj], s = fc[2*jj+1];
        qr[2*jj]     = xa * c - xb * s;
        qr[2*jj + 1] = xa * s + xb * c;
      }
      st8(po, qr);
      // U: l2norm + rope
      for (int jj = 0; jj < 4; ++jj) {
        float xa = crow[192 + dbase + 2*jj] * ui, xb = crow[192 + dbase + 2*jj + 1] * ui;
        float c = fc[2*jj], s = fc[2*jj+1];
        qr[2*jj]     = xa * c - xb * s;
        qr[2*jj + 1] = xa * s + xb * c;
      }
      st8(po + 3 * OUT_T, qr);
    }
    __syncthreads();
  }
}

extern "C" void kernel_launch(void* const* d_in, const int* in_sizes, int n_in,
                              void* d_out, int out_size, void* d_ws, size_t ws_size,
                              hipStream_t stream) {
  const float* X  = (const float*)d_in[0];
  const float* FC = (const float*)d_in[1];
  const float* wq = (const float*)d_in[2];
  const float* qb = (const float*)d_in[3];
  const float* wk = (const float*)d_in[4];
  const float* kb = (const float*)d_in[5];
  const float* wv = (const float*)d_in[6];
  const float* vb = (const float*)d_in[7];
  const float* wu = (const float*)d_in[8];
  const float* ub = (const float*)d_in[9];
  const float* tw = (const float*)d_in[10];
  const float* tb = (const float*)d_in[11];
  const float* lw = (const float*)d_in[12];
  const float* lb = (const float*)d_in[13];
  float* out = (float*)d_out;
  u16* WT = (u16*)d_ws;                             // 8 MB: 4x1024x1024 bf16
  float* E = (float*)((char*)d_ws + (8u << 20));    // 1 MB: 2*16*8192 f32
  u16* Xb = (u16*)((char*)d_ws + (9u << 20));       // 32 MB: 16384x1024 bf16

  hipLaunchKernelGGL(k_wt, dim3(1024), dim3(256), 0, stream, wq, wk, wv, wu, WT);
  hipLaunchKernelGGL(k_xbf, dim3(8192), dim3(256), 0, stream, X, Xb);
  hipLaunchKernelGGL(k_lr, dim3(4096), dim3(256), 0, stream, Xb, lw, lb, E);
  hipLaunchKernelGGL(k_main, dim3(4096), dim3(256), 0, stream,
                     Xb, FC, WT, qb, kb, vb, ub, tw, tb, out);
  hipLaunchKernelGGL(k_eta, dim3(16384), dim3(256), 0, stream, E, out);
}

// Round 4
// 230.118 us; speedup vs baseline: 1.5500x; 1.2939x over previous
//
#include <hip/hip_runtime.h>

typedef unsigned int u32;
typedef unsigned short u16;
typedef short short8v __attribute__((ext_vector_type(8)));
typedef float f32x4 __attribute__((ext_vector_type(4)));

#define ND 1024
#define NH 16
#define OUT_T ((size_t)16777216)  // 2*16*8192*64 elements per stacked tensor

__device__ __forceinline__ u16 f2bf(float f) {
  u32 u = __float_as_uint(f);
  u32 r = u + 0x7fffu + ((u >> 16) & 1u);
  return (u16)(r >> 16);
}

__device__ __forceinline__ short8v pack8(float4 a, float4 b) {
  short8v v;
  v[0] = (short)f2bf(a.x); v[1] = (short)f2bf(a.y);
  v[2] = (short)f2bf(a.z); v[3] = (short)f2bf(a.w);
  v[4] = (short)f2bf(b.x); v[5] = (short)f2bf(b.y);
  v[6] = (short)f2bf(b.z); v[7] = (short)f2bf(b.w);
  return v;
}

__device__ __forceinline__ void st8(float* p, const float* v) {
  for (int i = 0; i < 2; ++i) {
    f32x4 t; t[0] = v[4*i]; t[1] = v[4*i+1]; t[2] = v[4*i+2]; t[3] = v[4*i+3];
    *(f32x4*)(p + 4*i) = t;
  }
}

__device__ __forceinline__ void gload16(const void* g, void* l) {
  __builtin_amdgcn_global_load_lds((const __attribute__((address_space(1))) void*)g,
                                   (__attribute__((address_space(3))) void*)l, 16, 0, 0);
}

// ---- kernel 0: weights -> WT[w][c][kswz] bf16, transposed + swizzled ----
// stored position of original 16B k-chunk kc (8 bf16) is kc ^ (c&7)
__global__ void k_wt(const float* __restrict__ w0, const float* __restrict__ w1,
                     const float* __restrict__ w2, const float* __restrict__ w3,
                     u16* __restrict__ WT) {
  __shared__ float T[64][65];
  int bid = blockIdx.x;
  int w = bid >> 8;
  int tk = (bid >> 4) & 15, tc = bid & 15;
  const float* W = w == 0 ? w0 : w == 1 ? w1 : w == 2 ? w2 : w3;
  int k0 = tk << 6, c0 = tc << 6;
  int tid = threadIdx.x;
  for (int it = 0; it < 16; ++it) {
    int idx = it * 256 + tid;
    int kk = idx >> 6, cc = idx & 63;
    T[kk][cc] = W[(size_t)(k0 + kk) * ND + c0 + cc];
  }
  __syncthreads();
  for (int it = 0; it < 2; ++it) {
    int ci = it * 256 + tid;
    int cc = ci >> 3, k8 = ci & 7;
    int c = c0 + cc;
    short8v v;
    for (int j = 0; j < 8; ++j) v[j] = (short)f2bf(T[k8 * 8 + j][cc]);
    size_t off = ((size_t)(w * ND + c) << 10) + k0 + (((k8 ^ c) & 7) << 3);
    *(short8v*)(WT + off) = v;
  }
}

// ---- kernel 0b: X f32 -> bf16 ----
__global__ void k_xbf(const float* __restrict__ X, u16* __restrict__ Xb) {
  size_t i = ((size_t)blockIdx.x * 256 + threadIdx.x) * 8;
  float4 a = *(const float4*)(X + i), b = *(const float4*)(X + i + 4);
  *(short8v*)(Xb + i) = pack8(a, b);
}

// ---- kernel 1: lr proj via MFMA + sigmoid + direct eta writes ----
// block = one 64-token source chunk n; 256 thr (4 waves, 16 tokens each).
__global__ __launch_bounds__(256) void k_lr2(const u16* __restrict__ Xb,
                                             const float* __restrict__ LW,
                                             const float* __restrict__ LB,
                                             float* __restrict__ out) {
  __shared__ __align__(16) char smem[46080];
  u16* LWs = (u16*)smem;               // [16][1024] bf16, chunk-swizzled (32KB)
  u16* As = (u16*)(smem + 32768);      // [64][64] bf16, chunk-swizzled (8KB)
  float* El = (float*)(smem + 40960);  // [16 h][72] f32
  const int tid = threadIdx.x, lane = tid & 63, wid = tid >> 6;
  const int l15 = lane & 15, lg = lane >> 4;
  const int n = blockIdx.x;            // global chunk 0..255
  const int tok0 = n << 6;

  // stage LW -> LWs (bf16, swizzled), once
  {
    int row = tid >> 4;
    int cbase = (tid & 15) << 3;
    const float* src = LW + row * ND + (cbase << 3);
    for (int i = 0; i < 8; ++i) {
      float4 a = *(const float4*)(src + i * 8);
      float4 b = *(const float4*)(src + i * 8 + 4);
      int sc = (cbase + i) ^ (row & 7);  // low-3-bit xor (cbase mult of 8)
      *(short8v*)(LWs + row * 1024 + (sc << 3)) = pack8(a, b);
    }
  }

  const int arow0 = (wid << 4) + (lane >> 3);
  const u16* asrc = Xb + (size_t)(tok0 + arow0) * ND + ((((lane & 7) ^ arow0) & 7) << 3);
  const u32 aldo = wid << 10;
  const int aoff = ((wid << 4) + l15) << 6;
  const int key = l15 & 7;

  f32x4 acc;
  for (int r = 0; r < 4; ++r) acc[r] = 0.f;
  __syncthreads();  // LWs ready

  for (int kt = 0; kt < 16; ++kt) {
    gload16(asrc + (kt << 6), As + aldo);
    gload16(asrc + (kt << 6) + 8 * ND, As + aldo + 512);
    __syncthreads();
    for (int ks = 0; ks < 2; ++ks) {
      int kcl = (ks << 2) + lg;            // chunk within this K-tile
      int kcg = (kt << 3) + kcl;           // global chunk 0..127
      short8v af = *(const short8v*)(As + aoff + ((kcl ^ key) << 3));
      short8v bf = *(const short8v*)(LWs + (l15 << 10) + ((kcg ^ key) << 3));
      acc = __builtin_amdgcn_mfma_f32_16x16x32_bf16(af, bf, acc, 0, 0, 0);
    }
    __syncthreads();
  }

  // sigmoid -> El[h][k]
  for (int rr = 0; rr < 4; ++rr) {
    float v = acc[rr] + LB[l15];
    float e = (1.f / (1.f + expf(-v))) * (1.f / 4096.f);
    El[l15 * 72 + (wid << 4) + (lg << 2) + rr] = e;
  }
  __syncthreads();

  // eta: dst chunk pc from src chunk nl; 64 identical rows per (b,h)
  const int b = n >> 7, nl = n & 127;
  int q, rc;
  if (nl < 4) { q = nl; rc = 0; }
  else { q = (nl - 4) / 31; rc = nl - 3 - 31 * q; }
  const int pc = q * 32 + rc;
  const int j = tid >> 2, kq = tid & 3;
  size_t base = 4 * OUT_T + (((size_t)(b * NH) << 13) + (pc << 6)) * 64 + (size_t)j * 64;
  for (int h = 0; h < 16; ++h) {
    float* po = out + base + ((size_t)h << 19);
    for (int qq = 0; qq < 4; ++qq) {
      int k0 = (kq + (qq << 2)) << 2;
      const float* ep = El + h * 72 + k0;
      f32x4 t; t[0] = ep[0]; t[1] = ep[1]; t[2] = ep[2]; t[3] = ep[3];
      *(f32x4*)(po + k0) = t;
    }
  }
}

// ---- kernel 2: main fused GEMM + epilogue + permuted scatter ----
// block: 512 thr (8 waves 2x4), tile 256 tokens x 256 cols (head h: q|k|v|u)
// double-buffered LDS, one barrier per K-step; h-outer XCD mapping.
__global__ __launch_bounds__(512, 2) void k_main(
    const u16* __restrict__ Xb, const float* __restrict__ FC,
    const u16* __restrict__ WT,
    const float* __restrict__ qb, const float* __restrict__ kb,
    const float* __restrict__ vb, const float* __restrict__ ub,
    const float* __restrict__ tw, const float* __restrict__ tb,
    float* __restrict__ out) {
  __shared__ __align__(16) char smem[131072];
  // buf b: A @ b*65536 (32KB, [256][64] swizzled), B @ b*65536+32768 (32KB)
  float* Cs = (float*)smem;  // [64][261] f32 epilogue slab (aliases, post-K)

  const int tid = threadIdx.x;
  const int lane = tid & 63;
  const int wid = tid >> 6;
  const int wm = wid >> 2, wn = wid & 3;
  const int l15 = lane & 15, lg = lane >> 4;
  // h-outer: XCD x owns heads 2x,2x+1 -> its 1MB of WT stays L2-resident
  const int xcd = blockIdx.x & 7;
  const int local = blockIdx.x >> 3;          // 0..127
  const int h = (xcd << 1) | (local >> 6);
  const int s0 = (local & 63) << 8;

  f32x4 acc[8][4];
  for (int i = 0; i < 8; ++i)
    for (int j = 0; j < 4; ++j)
      for (int r = 0; r < 4; ++r) acc[i][j][r] = 0.f;

  const float* bp = (wn == 0) ? qb : (wn == 1) ? kb : (wn == 2) ? vb : ub;
  float biasv[4];
  for (int fn = 0; fn < 4; ++fn) biasv[fn] = bp[h * 64 + fn * 16 + l15];

  // A staging: wave stages rows wid*32..+31 (4 x 1KB gloads)
  const int arow0 = (wid << 5) + (lane >> 3);
  const u16* asrc = Xb + (size_t)(s0 + arow0) * ND + ((((lane & 7) ^ arow0) & 7) << 3);
  const u32 aldo = wid << 11;
  // B staging: wave stages B rows wid*32..+31 = weight wid>>1, d-half wid&1
  const int brow_d = ((wid & 1) << 5) + (lane >> 3);
  const u16* bsrc = WT + (((size_t)((wid >> 1) * ND + h * 64 + brow_d)) << 10) + ((lane & 7) << 3);
  const u32 bldo = wid << 11;

  int aoff[8], akey[8], boff[4], bkey[4];
  for (int f = 0; f < 8; ++f) {
    int ra = (wm << 7) + (f << 4) + l15;
    aoff[f] = ra << 6; akey[f] = ra & 7;
  }
  for (int f = 0; f < 4; ++f) {
    int rb = (wn << 6) + (f << 4) + l15;
    boff[f] = rb << 6; bkey[f] = rb & 7;
  }

  // prologue: stage kt=0 into buf0
  for (int j = 0; j < 4; ++j) {
    gload16(asrc + j * (8 * ND), (u16*)smem + aldo + (j << 9));
    gload16(bsrc + j * 8192, (u16*)(smem + 32768) + bldo + (j << 9));
  }
  __syncthreads();

  for (int kt = 0; kt < 16; ++kt) {
    const int cur = kt & 1;
    if (kt < 15) {  // issue next-tile stage FIRST (overlaps with compute below)
      const int k0 = (kt + 1) << 6;
      u16* ad = (u16*)(smem + ((cur ^ 1) << 16));
      u16* bd = (u16*)(smem + 32768 + ((cur ^ 1) << 16));
      for (int j = 0; j < 4; ++j) {
        gload16(asrc + k0 + j * (8 * ND), ad + aldo + (j << 9));
        gload16(bsrc + k0 + j * 8192, bd + bldo + (j << 9));
      }
    }
    const u16* As = (const u16*)(smem + (cur << 16));
    const u16* Bs = (const u16*)(smem + 32768 + (cur << 16));
    for (int ks = 0; ks < 2; ++ks) {
      const int kc = (ks << 2) + lg;
      short8v af[8], bf[4];
      for (int f = 0; f < 8; ++f)
        af[f] = *(const short8v*)(As + aoff[f] + ((kc ^ akey[f]) << 3));
      for (int f = 0; f < 4; ++f)
        bf[f] = *(const short8v*)(Bs + boff[f] + ((kc ^ bkey[f]) << 3));
      for (int fm = 0; fm < 8; ++fm)
        for (int fn = 0; fn < 4; ++fn)
          acc[fm][fn] = __builtin_amdgcn_mfma_f32_16x16x32_bf16(
              af[fm], bf[fn], acc[fm][fn], 0, 0, 0);
    }
    __syncthreads();  // drains this wave's gloads; next tile ready, bufs swap-safe
  }

  // epilogue: four 64-token phases through Cs
  for (int ph = 0; ph < 4; ++ph) {
    if (wm == (ph >> 1)) {
      for (int f2 = 0; f2 < 4; ++f2) {
        int fm = ((ph & 1) << 2) + f2;
        for (int fn = 0; fn < 4; ++fn)
          for (int rr = 0; rr < 4; ++rr) {
            int rl = (f2 << 4) + (lg << 2) + rr;
            int col = (wn << 6) + (fn << 4) + l15;
            Cs[rl * 261 + col] = acc[fm][fn][rr] + biasv[fn];
          }
      }
    }
    __syncthreads();
    {
      int tloc = tid >> 3, o = tid & 7;
      int dbase = o << 3;
      int stok = s0 + (ph << 6) + tloc;
      int b = stok >> 13, seq = stok & 8191;
      const float* crow = Cs + tloc * 261;
      float fc[8];
      {
        const f32x4* fp = (const f32x4*)(FC + ((size_t)seq << 6) + dbase);
        f32x4 t0 = fp[0], t1 = fp[1];
        fc[0] = t0[0]; fc[1] = t0[1]; fc[2] = t0[2]; fc[3] = t0[3];
        fc[4] = t1[0]; fc[5] = t1[1]; fc[6] = t1[2]; fc[7] = t1[3];
      }
      float sq = 0.f, sk = 0.f, su = 0.f;
      for (int j = 0; j < 8; ++j) {
        float a = crow[dbase + j], b2 = crow[64 + dbase + j], c = crow[192 + dbase + j];
        sq += a * a; sk += b2 * b2; su += c * c;
      }
      sq += __shfl_xor(sq, 1); sq += __shfl_xor(sq, 2); sq += __shfl_xor(sq, 4);
      sk += __shfl_xor(sk, 1); sk += __shfl_xor(sk, 2); sk += __shfl_xor(sk, 4);
      su += __shfl_xor(su, 1); su += __shfl_xor(su, 2); su += __shfl_xor(su, 4);
      float qi = 1.f / fmaxf(sqrtf(sq), 1e-12f);
      float ki = 1.f / fmaxf(sqrtf(sk), 1e-12f);
      float ui = 1.f / fmaxf(sqrtf(su), 1e-12f);
      int p;
      if (seq < 256) p = ((seq >> 6) << 11) + (seq & 63);
      else { int v = seq - 256; int qc = v / 1984; p = (qc << 11) + 64 + (v - qc * 1984); }
      float* po = out + ((((size_t)(b * NH + h) << 13) + p) << 6) + dbase;
      float kr[8];
      for (int jj = 0; jj < 4; ++jj) {
        float xa = crow[64 + dbase + 2*jj] * ki, xb = crow[64 + dbase + 2*jj + 1] * ki;
        float c = fc[2*jj], s = fc[2*jj+1];
        kr[2*jj]     = xa * c - xb * s;
        kr[2*jj + 1] = xa * s + xb * c;
      }
      st8(po + OUT_T, kr);
      float sd = 0.f, sdd = 0.f, df[8];
      for (int j = 0; j < 8; ++j) {
        df[j] = crow[128 + dbase + j] - kr[j];
        sd += df[j]; sdd += df[j] * df[j];
      }
      sd += __shfl_xor(sd, 1); sd += __shfl_xor(sd, 2); sd += __shfl_xor(sd, 4);
      sdd += __shfl_xor(sdd, 1); sdd += __shfl_xor(sdd, 2); sdd += __shfl_xor(sdd, 4);
      float mean = sd * (1.f / 64.f);
      float var = (sdd - sd * sd * (1.f / 64.f)) * (1.f / 63.f);
      float istd = 1.f / (sqrtf(fmaxf(var, 0.f)) + 1e-8f);
      for (int j = 0; j < 8; ++j) {
        int d = dbase + j;
        df[j] = tw[h * 64 + d] * ((df[j] - mean) * istd) + tb[h * 64 + d] + kr[j];
      }
      st8(po + 2 * OUT_T, df);
      float qr[8];
      for (int jj = 0; jj < 4; ++jj) {
        float xa = crow[dbase + 2*jj] * qi, xb = crow[dbase + 2*jj + 1] * qi;
        float c = fc[2*jj], s = fc[2*jj+1];
        qr[2*jj]     = xa * c - xb * s;
        qr[2*jj + 1] = xa * s + xb * c;
      }
      st8(po, qr);
      for (int jj = 0; jj < 4; ++jj) {
        float xa = crow[192 + dbase + 2*jj] * ui, xb = crow[192 + dbase + 2*jj + 1] * ui;
        float c = fc[2*jj], s = fc[2*jj+1];
        qr[2*jj]     = xa * c - xb * s;
        qr[2*jj + 1] = xa * s + xb * c;
      }
      st8(po + 3 * OUT_T, qr);
    }
    __syncthreads();
  }
}

extern "C" void kernel_launch(void* const* d_in, const int* in_sizes, int n_in,
                              void* d_out, int out_size, void* d_ws, size_t ws_size,
                              hipStream_t stream) {
  const float* X  = (const float*)d_in[0];
  const float* FC = (const float*)d_in[1];
  const float* wq = (const float*)d_in[2];
  const float* qb = (const float*)d_in[3];
  const float* wk = (const float*)d_in[4];
  const float* kb = (const float*)d_in[5];
  const float* wv = (const float*)d_in[6];
  const float* vb = (const float*)d_in[7];
  const float* wu = (const float*)d_in[8];
  const float* ub = (const float*)d_in[9];
  const float* tw = (const float*)d_in[10];
  const float* tb = (const float*)d_in[11];
  const float* lw = (const float*)d_in[12];
  const float* lb = (const float*)d_in[13];
  float* out = (float*)d_out;
  u16* WT = (u16*)d_ws;                           // 8 MB: 4x1024x1024 bf16
  u16* Xb = (u16*)((char*)d_ws + (8u << 20));     // 32 MB: 16384x1024 bf16

  hipLaunchKernelGGL(k_wt, dim3(1024), dim3(256), 0, stream, wq, wk, wv, wu, WT);
  hipLaunchKernelGGL(k_xbf, dim3(8192), dim3(256), 0, stream, X, Xb);
  hipLaunchKernelGGL(k_lr2, dim3(256), dim3(256), 0, stream, Xb, lw, lb, out);
  hipLaunchKernelGGL(k_main, dim3(1024), dim3(512), 0, stream,
                     Xb, FC, WT, qb, kb, vb, ub, tw, tb, out);
}